// Round 1
// baseline (531.551 us; speedup 1.0000x reference)
//
#include <hip/hip_runtime.h>

#define BLK 256
#define CHUNK 1024

// Pass 1: bucket-sum of exp(log_h) keyed by duration bucket.
__global__ void k_hist(const float* __restrict__ dur, const float* __restrict__ logh,
                       float* __restrict__ Q, int n, int B) {
    int stride = gridDim.x * blockDim.x;
    float fB = (float)B;
    for (int i = blockIdx.x * blockDim.x + threadIdx.x; i < n; i += stride) {
        float d = dur[i];
        int b = (int)(d * fB);
        b = b < 0 ? 0 : (b >= B ? B - 1 : b);
        atomicAdd(&Q[b], __expf(logh[i]));
    }
}

// Pass 2a: per-chunk (1024 buckets) total.
__global__ void k_chunk_reduce(const float* __restrict__ Q, float* __restrict__ chunkSum) {
    __shared__ float s[256];
    int c = blockIdx.x;
    const float* p = Q + (size_t)c * CHUNK;
    float v = 0.f;
    for (int t = threadIdx.x; t < CHUNK; t += 256) v += p[t];
    s[threadIdx.x] = v;
    __syncthreads();
    for (int off = 128; off > 0; off >>= 1) {
        if (threadIdx.x < off) s[threadIdx.x] += s[threadIdx.x + off];
        __syncthreads();
    }
    if (threadIdx.x == 0) chunkSum[c] = s[0];
}

// Pass 2b: exclusive suffix scan over chunk sums (single block, <=1024 chunks).
__global__ void k_chunk_scan(const float* __restrict__ chunkSum,
                             float* __restrict__ chunkSufExcl, int nchunk) {
    __shared__ float a[1024], b[1024];
    int t = threadIdx.x;
    a[t] = (t < nchunk) ? chunkSum[t] : 0.f;
    __syncthreads();
    float* src = a;
    float* dst = b;
    for (int off = 1; off < 1024; off <<= 1) {
        float v = src[t] + ((t + off < 1024) ? src[t + off] : 0.f);
        dst[t] = v;
        __syncthreads();
        float* tmp = src; src = dst; dst = tmp;
    }
    // src[t] = inclusive suffix sum; exclusive = next element's inclusive.
    if (t < nchunk) chunkSufExcl[t] = (t + 1 < 1024) ? src[t + 1] : 0.f;
}

// Pass 2c: full per-bucket exclusive suffix sums T[b] = sum_{b' > b} Q[b'].
__global__ void k_chunk_suffix(const float* __restrict__ Q,
                               const float* __restrict__ chunkSufExcl,
                               float* __restrict__ T) {
    __shared__ float a[1024], b[1024];
    int c = blockIdx.x;
    int t = threadIdx.x;
    size_t idx = (size_t)c * CHUNK + t;
    a[t] = Q[idx];
    __syncthreads();
    float* src = a;
    float* dst = b;
    for (int off = 1; off < 1024; off <<= 1) {
        float v = src[t] + ((t + off < 1024) ? src[t + off] : 0.f);
        dst[t] = v;
        __syncthreads();
        float* tmp = src; src = dst; dst = tmp;
    }
    float excl = (t + 1 < 1024) ? src[t + 1] : 0.f;
    T[idx] = excl + chunkSufExcl[c];
}

// Pass 3: loss = sum over events of (log(S_i) - slh_i),
// S_i ~= T[b] + 0.5*(Q[b] + exp(slh_i))  (midpoint within-bucket approximation).
__global__ void k_finalize(const float* __restrict__ dur, const float* __restrict__ logh,
                           const int* __restrict__ ev, const float* __restrict__ Q,
                           const float* __restrict__ T, float* __restrict__ out,
                           int n, int B) {
    float local = 0.f;
    int stride = gridDim.x * blockDim.x;
    float fB = (float)B;
    for (int i = blockIdx.x * blockDim.x + threadIdx.x; i < n; i += stride) {
        int e = ev[i];
        float d = dur[i];
        float slh = logh[i];
        if (e) {
            int b = (int)(d * fB);
            b = b < 0 ? 0 : (b >= B ? B - 1 : b);
            float ex = __expf(slh);
            float S = T[b] + 0.5f * (Q[b] + ex);
            local += __logf(S) - slh;
        }
    }
    __shared__ float s[BLK];
    s[threadIdx.x] = local;
    __syncthreads();
    for (int off = BLK / 2; off > 0; off >>= 1) {
        if (threadIdx.x < off) s[threadIdx.x] += s[threadIdx.x + off];
        __syncthreads();
    }
    if (threadIdx.x == 0) atomicAdd(out, s[0]);
}

extern "C" void kernel_launch(void* const* d_in, const int* in_sizes, int n_in,
                              void* d_out, int out_size, void* d_ws, size_t ws_size,
                              hipStream_t stream) {
    const float* logh = (const float*)d_in[0];   // log_h
    const float* dur  = (const float*)d_in[1];   // durations
    const int*   ev   = (const int*)d_in[2];     // events
    float* out = (float*)d_out;
    int n = in_sizes[0];

    // Pick bucket count that fits the workspace: Q[B] + T[B] + 2*nchunk floats.
    int B = 1 << 20;
    while ((size_t)B * 2 * sizeof(float) + 4 * (size_t)(B / CHUNK) * sizeof(float) + 1024 > ws_size
           && B > CHUNK) {
        B >>= 1;
    }
    int nchunk = B / CHUNK;

    float* Q   = (float*)d_ws;
    float* T   = Q + B;
    float* cs  = T + B;
    float* cse = cs + nchunk;

    hipMemsetAsync(Q, 0, (size_t)B * sizeof(float), stream);
    hipMemsetAsync(out, 0, sizeof(float), stream);

    k_hist<<<2048, BLK, 0, stream>>>(dur, logh, Q, n, B);
    k_chunk_reduce<<<nchunk, 256, 0, stream>>>(Q, cs);
    k_chunk_scan<<<1, 1024, 0, stream>>>(cs, cse, nchunk);
    k_chunk_suffix<<<nchunk, 1024, 0, stream>>>(Q, cse, T);
    k_finalize<<<2048, BLK, 0, stream>>>(dur, logh, ev, Q, T, out, n, B);
}

// Round 2
// 226.844 us; speedup vs baseline: 2.3432x; 2.3432x over previous
//
#include <hip/hip_runtime.h>

#define BINS 8192
#define HIST_BLK 256
#define FIN_BLK 256

__device__ __forceinline__ int bin_of(float d) {
    int b = (int)(d * (float)BINS);
    return b < 0 ? 0 : (b >= BINS ? BINS - 1 : b);
}

// Pass 1: per-block LDS histogram of exp(log_h) keyed by duration bin,
// dumped non-atomically to partial[g][BINS].
__global__ void k_hist_lds(const float4* __restrict__ dur4,
                           const float4* __restrict__ logh4,
                           float* __restrict__ partial, int n4, int G) {
    __shared__ float h[BINS];
    for (int i = threadIdx.x; i < BINS; i += HIST_BLK) h[i] = 0.f;
    __syncthreads();
    int stride = G * HIST_BLK;
    for (int i = blockIdx.x * HIST_BLK + threadIdx.x; i < n4; i += stride) {
        float4 d  = dur4[i];
        float4 lh = logh4[i];
        atomicAdd(&h[bin_of(d.x)], __expf(lh.x));
        atomicAdd(&h[bin_of(d.y)], __expf(lh.y));
        atomicAdd(&h[bin_of(d.z)], __expf(lh.z));
        atomicAdd(&h[bin_of(d.w)], __expf(lh.w));
    }
    __syncthreads();
    float* p = partial + (size_t)blockIdx.x * BINS;
    for (int i = threadIdx.x; i < BINS; i += HIST_BLK) p[i] = h[i];
}

// Pass 2: Q[b] = sum_g partial[g][b]  (coalesced across threads).
__global__ void k_merge(const float* __restrict__ partial, float* __restrict__ Q, int G) {
    int b = blockIdx.x * 256 + threadIdx.x;
    float v = 0.f;
    for (int g = 0; g < G; ++g) v += partial[(size_t)g * BINS + b];
    Q[b] = v;
}

// Pass 3: exclusive suffix sums T[b] = sum_{b' > b} Q[b'], single block.
__global__ void k_scan(const float* __restrict__ Q, float* __restrict__ T) {
    __shared__ float ps[1024];
    __shared__ float pd[1024];
    int t = threadIdx.x;
    float q[8], s[8];
    const float* p = Q + t * 8;
#pragma unroll
    for (int j = 0; j < 8; ++j) q[j] = p[j];
    float run = 0.f;
#pragma unroll
    for (int j = 7; j >= 0; --j) { run += q[j]; s[j] = run; }  // inclusive suffix in chunk
    ps[t] = run;
    __syncthreads();
    float* src = ps;
    float* dst = pd;
    for (int off = 1; off < 1024; off <<= 1) {
        float v = src[t] + ((t + off < 1024) ? src[t + off] : 0.f);
        dst[t] = v;
        __syncthreads();
        float* tmp = src; src = dst; dst = tmp;
    }
    float excl = (t + 1 < 1024) ? src[t + 1] : 0.f;  // sum over later chunks
    float* o = T + t * 8;
#pragma unroll
    for (int j = 0; j < 8; ++j) o[j] = excl + s[j] - q[j];  // strictly-after bins
}

// Pass 4: loss = sum over events of (log(S_i) - slh_i),
// S_i ~= T[b] + 0.5*(Q[b] + exp(slh_i))   (midpoint within-bin approximation).
__global__ void k_finalize(const float4* __restrict__ dur4,
                           const float4* __restrict__ logh4,
                           const int4* __restrict__ ev4,
                           const float* __restrict__ Q, const float* __restrict__ T,
                           float* __restrict__ out, int n4) {
    float local = 0.f;
    int stride = gridDim.x * blockDim.x;
    for (int i = blockIdx.x * blockDim.x + threadIdx.x; i < n4; i += stride) {
        float4 d  = dur4[i];
        float4 lh = logh4[i];
        int4   e  = ev4[i];
        {
            int b = bin_of(d.x); float ex = __expf(lh.x);
            local += (float)e.x * (__logf(T[b] + 0.5f * (Q[b] + ex)) - lh.x);
        }
        {
            int b = bin_of(d.y); float ex = __expf(lh.y);
            local += (float)e.y * (__logf(T[b] + 0.5f * (Q[b] + ex)) - lh.y);
        }
        {
            int b = bin_of(d.z); float ex = __expf(lh.z);
            local += (float)e.z * (__logf(T[b] + 0.5f * (Q[b] + ex)) - lh.z);
        }
        {
            int b = bin_of(d.w); float ex = __expf(lh.w);
            local += (float)e.w * (__logf(T[b] + 0.5f * (Q[b] + ex)) - lh.w);
        }
    }
    __shared__ float s[FIN_BLK];
    s[threadIdx.x] = local;
    __syncthreads();
    for (int off = FIN_BLK / 2; off > 0; off >>= 1) {
        if (threadIdx.x < off) s[threadIdx.x] += s[threadIdx.x + off];
        __syncthreads();
    }
    if (threadIdx.x == 0) atomicAdd(out, s[0]);
}

extern "C" void kernel_launch(void* const* d_in, const int* in_sizes, int n_in,
                              void* d_out, int out_size, void* d_ws, size_t ws_size,
                              hipStream_t stream) {
    const float* logh = (const float*)d_in[0];
    const float* dur  = (const float*)d_in[1];
    const int*   ev   = (const int*)d_in[2];
    float* out = (float*)d_out;
    int n = in_sizes[0];
    int n4 = n / 4;  // N = 8388608, divisible by 4

    // Workspace: partial[G][BINS] + Q[BINS] + T[BINS]
    int G = 512;
    while ((size_t)G * BINS * sizeof(float) + 2 * (size_t)BINS * sizeof(float) > ws_size
           && G > 8) {
        G >>= 1;
    }
    float* partial = (float*)d_ws;
    float* Q = partial + (size_t)G * BINS;
    float* T = Q + BINS;

    hipMemsetAsync(out, 0, sizeof(float), stream);

    k_hist_lds<<<G, HIST_BLK, 0, stream>>>((const float4*)dur, (const float4*)logh,
                                           partial, n4, G);
    k_merge<<<BINS / 256, 256, 0, stream>>>(partial, Q, G);
    k_scan<<<1, 1024, 0, stream>>>(Q, T);
    k_finalize<<<2048, FIN_BLK, 0, stream>>>((const float4*)dur, (const float4*)logh,
                                             (const int4*)ev, Q, T, out, n4);
}

// Round 3
// 120.715 us; speedup vs baseline: 4.4034x; 1.8792x over previous
//
#include <hip/hip_runtime.h>

#define BINS 8192
#define BINS4 (BINS / 4)
#define HIST_BLK 256
#define FIN_BLK 256
#define SPLIT 16

__device__ __forceinline__ int bin_of(float d) {
    int b = (int)(d * (float)BINS);
    return b < 0 ? 0 : (b >= BINS ? BINS - 1 : b);
}

// Pass 1: per-block LDS histogram of exp(log_h) keyed by duration bin,
// dumped non-atomically to partial[g][BINS].
__global__ void k_hist_lds(const float4* __restrict__ dur4,
                           const float4* __restrict__ logh4,
                           float* __restrict__ partial, int n4, int G) {
    __shared__ float h[BINS];
    for (int i = threadIdx.x; i < BINS; i += HIST_BLK) h[i] = 0.f;
    __syncthreads();
    int stride = G * HIST_BLK;
    for (int i = blockIdx.x * HIST_BLK + threadIdx.x; i < n4; i += stride) {
        float4 d  = dur4[i];
        float4 lh = logh4[i];
        atomicAdd(&h[bin_of(d.x)], __expf(lh.x));
        atomicAdd(&h[bin_of(d.y)], __expf(lh.y));
        atomicAdd(&h[bin_of(d.z)], __expf(lh.z));
        atomicAdd(&h[bin_of(d.w)], __expf(lh.w));
    }
    __syncthreads();
    float* p = partial + (size_t)blockIdx.x * BINS;
    for (int i = threadIdx.x; i < BINS; i += HIST_BLK) p[i] = h[i];
}

// Pass 2a: QP[gs][b] = sum over rows of the gs-th G-slice.
// Grid: 8 bin-chunks x SPLIT g-slices = 8*SPLIT blocks, 256 threads.
__global__ void k_merge_a(const float4* __restrict__ partial4,
                          float4* __restrict__ QP4, int rows) {
    int bc = blockIdx.x & 7;        // bin chunk: 1024 bins = 256 float4
    int gs = blockIdx.x >> 3;       // g-slice
    int b4 = bc * 256 + threadIdx.x;
    const float4* base = partial4 + (size_t)gs * rows * BINS4 + b4;
    float4 acc = {0.f, 0.f, 0.f, 0.f};
    for (int k = 0; k < rows; ++k) {
        float4 v = base[(size_t)k * BINS4];
        acc.x += v.x; acc.y += v.y; acc.z += v.z; acc.w += v.w;
    }
    QP4[(size_t)gs * BINS4 + b4] = acc;
}

// Pass 2b: Q[b] = sum over the SPLIT slices. Grid: 8 blocks x 256 threads.
__global__ void k_merge_b(const float4* __restrict__ QP4, float4* __restrict__ Q4) {
    int b4 = blockIdx.x * 256 + threadIdx.x;
    float4 acc = {0.f, 0.f, 0.f, 0.f};
#pragma unroll
    for (int gs = 0; gs < SPLIT; ++gs) {
        float4 v = QP4[(size_t)gs * BINS4 + b4];
        acc.x += v.x; acc.y += v.y; acc.z += v.z; acc.w += v.w;
    }
    Q4[b4] = acc;
}

// Pass 3: exclusive suffix sums T[b] = sum_{b' > b} Q[b'], single block.
__global__ void k_scan(const float* __restrict__ Q, float* __restrict__ T) {
    __shared__ float ps[1024];
    __shared__ float pd[1024];
    int t = threadIdx.x;
    float q[8], s[8];
    const float* p = Q + t * 8;
#pragma unroll
    for (int j = 0; j < 8; ++j) q[j] = p[j];
    float run = 0.f;
#pragma unroll
    for (int j = 7; j >= 0; --j) { run += q[j]; s[j] = run; }  // inclusive suffix in chunk
    ps[t] = run;
    __syncthreads();
    float* src = ps;
    float* dst = pd;
    for (int off = 1; off < 1024; off <<= 1) {
        float v = src[t] + ((t + off < 1024) ? src[t + off] : 0.f);
        dst[t] = v;
        __syncthreads();
        float* tmp = src; src = dst; dst = tmp;
    }
    float excl = (t + 1 < 1024) ? src[t + 1] : 0.f;  // sum over later chunks
    float* o = T + t * 8;
#pragma unroll
    for (int j = 0; j < 8; ++j) o[j] = excl + s[j] - q[j];  // strictly-after bins
}

// Pass 4: loss = sum over events of (log(S_i) - slh_i),
// S_i ~= T[b] + 0.5*(Q[b] + exp(slh_i))   (midpoint within-bin approximation).
__global__ void k_finalize(const float4* __restrict__ dur4,
                           const float4* __restrict__ logh4,
                           const int4* __restrict__ ev4,
                           const float* __restrict__ Q, const float* __restrict__ T,
                           float* __restrict__ out, int n4) {
    float local = 0.f;
    int stride = gridDim.x * blockDim.x;
    for (int i = blockIdx.x * blockDim.x + threadIdx.x; i < n4; i += stride) {
        float4 d  = dur4[i];
        float4 lh = logh4[i];
        int4   e  = ev4[i];
        {
            int b = bin_of(d.x); float ex = __expf(lh.x);
            local += (float)e.x * (__logf(T[b] + 0.5f * (Q[b] + ex)) - lh.x);
        }
        {
            int b = bin_of(d.y); float ex = __expf(lh.y);
            local += (float)e.y * (__logf(T[b] + 0.5f * (Q[b] + ex)) - lh.y);
        }
        {
            int b = bin_of(d.z); float ex = __expf(lh.z);
            local += (float)e.z * (__logf(T[b] + 0.5f * (Q[b] + ex)) - lh.z);
        }
        {
            int b = bin_of(d.w); float ex = __expf(lh.w);
            local += (float)e.w * (__logf(T[b] + 0.5f * (Q[b] + ex)) - lh.w);
        }
    }
    __shared__ float s[FIN_BLK];
    s[threadIdx.x] = local;
    __syncthreads();
    for (int off = FIN_BLK / 2; off > 0; off >>= 1) {
        if (threadIdx.x < off) s[threadIdx.x] += s[threadIdx.x + off];
        __syncthreads();
    }
    if (threadIdx.x == 0) atomicAdd(out, s[0]);
}

extern "C" void kernel_launch(void* const* d_in, const int* in_sizes, int n_in,
                              void* d_out, int out_size, void* d_ws, size_t ws_size,
                              hipStream_t stream) {
    const float* logh = (const float*)d_in[0];
    const float* dur  = (const float*)d_in[1];
    const int*   ev   = (const int*)d_in[2];
    float* out = (float*)d_out;
    int n = in_sizes[0];
    int n4 = n / 4;  // N = 8388608, divisible by 4

    // Workspace: partial[G][BINS] + QP[SPLIT][BINS] + Q[BINS] + T[BINS].
    // Choose G = largest multiple of SPLIT (<=512) that fits.
    size_t fixed = (size_t)(SPLIT + 2) * BINS * sizeof(float);
    long avail = (long)(ws_size - fixed);
    int G = (int)(avail / ((long)BINS * sizeof(float)));
    if (G > 512) G = 512;
    G &= ~(SPLIT - 1);           // multiple of SPLIT
    if (G < SPLIT) G = SPLIT;
    int rows = G / SPLIT;

    float* partial = (float*)d_ws;
    float* QP = partial + (size_t)G * BINS;
    float* Q  = QP + (size_t)SPLIT * BINS;
    float* T  = Q + BINS;

    hipMemsetAsync(out, 0, sizeof(float), stream);

    k_hist_lds<<<G, HIST_BLK, 0, stream>>>((const float4*)dur, (const float4*)logh,
                                           partial, n4, G);
    k_merge_a<<<8 * SPLIT, 256, 0, stream>>>((const float4*)partial, (float4*)QP, rows);
    k_merge_b<<<8, 256, 0, stream>>>((const float4*)QP, (float4*)Q);
    k_scan<<<1, 1024, 0, stream>>>(Q, T);
    k_finalize<<<2048, FIN_BLK, 0, stream>>>((const float4*)dur, (const float4*)logh,
                                             (const int4*)ev, Q, T, out, n4);
}